// Round 4
// baseline (76.674 us; speedup 1.0000x reference)
//
#include <hip/hip_runtime.h>
#include <hip/hip_fp16.h>

// DotProductDecoder: out[e] = sigmoid( dot(h[src[e]], h[dst[e]]) ), D=256.
//
// Structure (round 4): the fp16 table (25.6 MB) misses private 4MB per-XCD
// L2s under random access; the L2<-L3 fill path (~2.6 TB/s) was the ceiling.
// Fix: split D into 8 column-slices of 32 halves (64B = 1 cache line; slice
// table = 3.2 MB, fits one XCD's L2). Block b handles slice b%8 -> with
// round-robin block->XCD dispatch, each XCD gathers only from its own
// L2-resident slice. Partial dots go to d_ws; final kernel sums 8 + sigmoid.

typedef _Float16 half2_raw __attribute__((ext_vector_type(2)));

__global__ __launch_bounds__(256) void convert_f32_to_f16(
    const float* __restrict__ h, __half* __restrict__ hh, int n8)
{
    int i = blockIdx.x * blockDim.x + threadIdx.x;
    const int stride = gridDim.x * blockDim.x;
    for (; i < n8; i += stride) {
        float4 a = reinterpret_cast<const float4*>(h)[2 * i + 0];
        float4 b = reinterpret_cast<const float4*>(h)[2 * i + 1];
        __half2 p[4];
        p[0] = __floats2half2_rn(a.x, a.y);
        p[1] = __floats2half2_rn(a.z, a.w);
        p[2] = __floats2half2_rn(b.x, b.y);
        p[3] = __floats2half2_rn(b.z, b.w);
        reinterpret_cast<uint4*>(hh)[i] = *reinterpret_cast<uint4*>(p);
    }
}

__device__ inline float dot8_f16(const uint4& v, const uint4& w, float acc) {
#if __has_builtin(__builtin_amdgcn_fdot2)
    const half2_raw* pa = reinterpret_cast<const half2_raw*>(&v);
    const half2_raw* pb = reinterpret_cast<const half2_raw*>(&w);
    #pragma unroll
    for (int q = 0; q < 4; ++q)
        acc = __builtin_amdgcn_fdot2(pa[q], pb[q], acc, false);
#else
    const __half2* pa = reinterpret_cast<const __half2*>(&v);
    const __half2* pb = reinterpret_cast<const __half2*>(&w);
    #pragma unroll
    for (int q = 0; q < 4; ++q) {
        float2 fa = __half22float2(pa[q]);
        float2 fb = __half22float2(pb[q]);
        acc += fa.x * fb.x + fa.y * fb.y;
    }
#endif
    return acc;
}

// One slice-pass per XCD. 8 lanes per edge: lanes j=0..3 load src row-slice
// 16B chunks, j=4..7 load dst chunks. shfl_xor(4) pairs them, 2-step reduce.
__global__ __launch_bounds__(256) void slice_gather_dot(
    const __half* __restrict__ hh,
    const int*    __restrict__ src_idx,
    const int*    __restrict__ dst_idx,
    float*        __restrict__ partial,   // [8][E]
    int E)
{
    const int slice = blockIdx.x & 7;
    const int lane  = threadIdx.x & 63;
    const int j     = lane & 7;            // position within 8-lane edge-group
    const int g     = lane >> 3;           // edge-group 0..7 within wave
    const int wsl   = (blockIdx.x >> 3) * (blockDim.x >> 6) + (threadIdx.x >> 6);
    const int nwsl  = (gridDim.x >> 3) * (blockDim.x >> 6);

    const __half* hsl = hh + slice * 32;   // column offset of this slice
    float* psl = partial + (size_t)slice * E;

    for (int base = wsl * 8; base < E; base += nwsl * 8) {
        const int e  = base + g;
        const bool ok = (e < E);
        const int ec = ok ? e : 0;
        const int si = __builtin_nontemporal_load(src_idx + ec);
        const int di = __builtin_nontemporal_load(dst_idx + ec);
        const int idx = (j & 4) ? di : si;

        // 16B chunk (j&3) of the 64B row-slice; row-slice is 64B-aligned.
        const uint4 v = *reinterpret_cast<const uint4*>(
            hsl + (size_t)idx * 256 + (j & 3) * 8);

        uint4 w;
        w.x = __shfl_xor(v.x, 4, 64);
        w.y = __shfl_xor(v.y, 4, 64);
        w.z = __shfl_xor(v.z, 4, 64);
        w.w = __shfl_xor(v.w, 4, 64);

        float acc = dot8_f16(v, w, 0.0f);
        acc += __shfl_xor(acc, 1, 64);
        acc += __shfl_xor(acc, 2, 64);

        if (j == 0 && ok) __builtin_nontemporal_store(acc, psl + e);
    }
}

__global__ __launch_bounds__(256) void reduce_sigmoid(
    const float* __restrict__ partial, float* __restrict__ out, int E)
{
    int t = blockIdx.x * blockDim.x + threadIdx.x;
    const int stride = gridDim.x * blockDim.x;
    for (; t < E; t += stride) {
        float s = 0.0f;
        #pragma unroll
        for (int k = 0; k < 8; ++k)
            s += __builtin_nontemporal_load(partial + (size_t)k * E + t);
        out[t] = 1.0f / (1.0f + __expf(-s));
    }
}

// Fallback: whole-row fp16 gather (round-2 kernel), if ws can't hold partials.
__global__ __launch_bounds__(256) void gather_dot_f16(
    const __half* __restrict__ hh,
    const int*    __restrict__ src_idx,
    const int*    __restrict__ dst_idx,
    float*        __restrict__ out,
    int E)
{
    const int lane   = threadIdx.x & 63;
    const int wave   = (blockIdx.x * blockDim.x + threadIdx.x) >> 6;
    const int nwaves = (gridDim.x * blockDim.x) >> 6;
    for (int e = wave; e < E; e += nwaves) {
        const int s = src_idx[e];
        const int d = dst_idx[e];
        uint2 ua = *reinterpret_cast<const uint2*>(hh + (size_t)s * 256 + lane * 4);
        uint2 ub = *reinterpret_cast<const uint2*>(hh + (size_t)d * 256 + lane * 4);
        float2 a0 = __half22float2(*reinterpret_cast<__half2*>(&ua.x));
        float2 a1 = __half22float2(*reinterpret_cast<__half2*>(&ua.y));
        float2 b0 = __half22float2(*reinterpret_cast<__half2*>(&ub.x));
        float2 b1 = __half22float2(*reinterpret_cast<__half2*>(&ub.y));
        float acc = a0.x * b0.x + a0.y * b0.y + a1.x * b1.x + a1.y * b1.y;
        #pragma unroll
        for (int off = 32; off >= 1; off >>= 1)
            acc += __shfl_xor(acc, off, 64);
        if (lane == 0) out[e] = 1.0f / (1.0f + __expf(-acc));
    }
}

// fp32 fallback if workspace can't even hold the fp16 table.
__global__ __launch_bounds__(256) void gather_dot_f32(
    const float* __restrict__ h,
    const int*   __restrict__ src_idx,
    const int*   __restrict__ dst_idx,
    float*       __restrict__ out,
    int E)
{
    const int lane   = threadIdx.x & 63;
    const int wave   = (blockIdx.x * blockDim.x + threadIdx.x) >> 6;
    const int nwaves = (gridDim.x * blockDim.x) >> 6;
    for (int e = wave; e < E; e += nwaves) {
        const int s = src_idx[e];
        const int d = dst_idx[e];
        const float4 a = *reinterpret_cast<const float4*>(h + (size_t)s * 256 + lane * 4);
        const float4 b = *reinterpret_cast<const float4*>(h + (size_t)d * 256 + lane * 4);
        float acc = a.x * b.x + a.y * b.y + a.z * b.z + a.w * b.w;
        #pragma unroll
        for (int off = 32; off >= 1; off >>= 1)
            acc += __shfl_xor(acc, off, 64);
        if (lane == 0) out[e] = 1.0f / (1.0f + __expf(-acc));
    }
}

extern "C" void kernel_launch(void* const* d_in, const int* in_sizes, int n_in,
                              void* d_out, int out_size, void* d_ws, size_t ws_size,
                              hipStream_t stream) {
    const float* h   = (const float*)d_in[0];
    const int*   ei  = (const int*)d_in[1];   // [2, E]: src row then dst row
    float*       out = (float*)d_out;

    const int ND = in_sizes[0];               // N * 256
    const int E  = in_sizes[1] / 2;
    const int* src = ei;
    const int* dst = ei + E;

    const size_t tbl_bytes  = (size_t)ND * sizeof(__half);
    const size_t part_bytes = (size_t)8 * E * sizeof(float);

    if (ws_size >= tbl_bytes + part_bytes) {
        __half* hh      = (__half*)d_ws;
        float*  partial = (float*)((char*)d_ws + tbl_bytes);
        convert_f32_to_f16<<<2048, 256, 0, stream>>>(h, hh, ND / 8);
        slice_gather_dot<<<2048, 256, 0, stream>>>(hh, src, dst, partial, E);
        reduce_sigmoid<<<1024, 256, 0, stream>>>(partial, out, E);
    } else if (ws_size >= tbl_bytes) {
        __half* hh = (__half*)d_ws;
        convert_f32_to_f16<<<2048, 256, 0, stream>>>(h, hh, ND / 8);
        gather_dot_f16<<<2048, 256, 0, stream>>>(hh, src, dst, out, E);
    } else {
        gather_dot_f32<<<2048, 256, 0, stream>>>(h, src, dst, out, E);
    }
}

// Round 5
// 67.182 us; speedup vs baseline: 1.1413x; 1.1413x over previous
//
#include <hip/hip_runtime.h>
#include <hip/hip_fp16.h>

// DotProductDecoder: out[e] = sigmoid( dot(h[src[e]], h[dst[e]]) ), D=256.
//
// Round 5: slice-major layout. Round 4's D-slicing failed because 64B slices
// were interleaved inside 512B rows -> each 128B TCC line held TWO slices ->
// per-XCD footprint 6.4MB > 4MB L2. Now the fp16 table is stored as
// hs[slice][node][32 halves]: each slice is a contiguous 3.2MB table that
// fits one XCD's L2. Block b handles slice b&7 (round-robin block->XCD),
// gathers 64B row-slices L2-resident, writes partial dots; final kernel
// sums 8 partials + sigmoid.

typedef _Float16 half2_raw __attribute__((ext_vector_type(2)));

// Transpose-convert: one wave per node row. Lane l reads 16B (4 floats) of
// the fp32 row, converts to 8B fp16, writes into slice table l>>3 at
// sub-offset (l&7)*8B. Each 8-lane group stores 64B contiguous.
__global__ __launch_bounds__(256) void convert_slice_f16(
    const float* __restrict__ h, __half* __restrict__ hs, int N)
{
    const int lane   = threadIdx.x & 63;
    const int wave   = (blockIdx.x * blockDim.x + threadIdx.x) >> 6;
    const int nwaves = (gridDim.x * blockDim.x) >> 6;
    const int slice  = lane >> 3;
    const int sub    = lane & 7;

    for (int n = wave; n < N; n += nwaves) {
        float4 v = reinterpret_cast<const float4*>(h + (size_t)n * 256)[lane];
        __half2 p[2];
        p[0] = __floats2half2_rn(v.x, v.y);
        p[1] = __floats2half2_rn(v.z, v.w);
        reinterpret_cast<uint2*>(hs + ((size_t)slice * N + n) * 32)[sub] =
            *reinterpret_cast<uint2*>(p);
    }
}

__device__ inline float dot8_f16(const uint4& v, const uint4& w, float acc) {
#if __has_builtin(__builtin_amdgcn_fdot2)
    const half2_raw* pa = reinterpret_cast<const half2_raw*>(&v);
    const half2_raw* pb = reinterpret_cast<const half2_raw*>(&w);
    #pragma unroll
    for (int q = 0; q < 4; ++q)
        acc = __builtin_amdgcn_fdot2(pa[q], pb[q], acc, false);
#else
    const __half2* pa = reinterpret_cast<const __half2*>(&v);
    const __half2* pb = reinterpret_cast<const __half2*>(&w);
    #pragma unroll
    for (int q = 0; q < 4; ++q) {
        float2 fa = __half22float2(pa[q]);
        float2 fb = __half22float2(pb[q]);
        acc += fa.x * fb.x + fa.y * fb.y;
    }
#endif
    return acc;
}

// 8 lanes per edge: lanes j=0..3 load the src row-slice (4 x 16B = 64B),
// j=4..7 the dst row-slice. shfl_xor(4) pairs src/dst, 2-step reduce.
__global__ __launch_bounds__(256) void slice_gather_dot(
    const __half* __restrict__ hs,     // [8][N][32]
    const int*    __restrict__ src_idx,
    const int*    __restrict__ dst_idx,
    float*        __restrict__ partial, // [8][E]
    int E, int N)
{
    const int slice = blockIdx.x & 7;
    const int lane  = threadIdx.x & 63;
    const int j     = lane & 7;
    const int g     = lane >> 3;
    const int wsl   = (blockIdx.x >> 3) * (blockDim.x >> 6) + (threadIdx.x >> 6);
    const int nwsl  = (gridDim.x >> 3) * (blockDim.x >> 6);

    const __half* hsl = hs + (size_t)slice * N * 32;
    float* psl = partial + (size_t)slice * E;

    for (int base = wsl * 8; base < E; base += nwsl * 8) {
        const int e   = base + g;
        const bool ok = (e < E);
        const int ec  = ok ? e : 0;
        const int si  = __builtin_nontemporal_load(src_idx + ec);
        const int di  = __builtin_nontemporal_load(dst_idx + ec);
        const int idx = (j & 4) ? di : si;

        const uint4 v = *reinterpret_cast<const uint4*>(
            hsl + (size_t)idx * 32 + (j & 3) * 8);

        uint4 w;
        w.x = __shfl_xor(v.x, 4, 64);
        w.y = __shfl_xor(v.y, 4, 64);
        w.z = __shfl_xor(v.z, 4, 64);
        w.w = __shfl_xor(v.w, 4, 64);

        float acc = dot8_f16(v, w, 0.0f);
        acc += __shfl_xor(acc, 1, 64);
        acc += __shfl_xor(acc, 2, 64);

        if (j == 0 && ok) __builtin_nontemporal_store(acc, psl + e);
    }
}

__global__ __launch_bounds__(256) void reduce_sigmoid(
    const float* __restrict__ partial, float* __restrict__ out, int E)
{
    int t = blockIdx.x * blockDim.x + threadIdx.x;
    const int stride = gridDim.x * blockDim.x;
    for (; t < E; t += stride) {
        float s = 0.0f;
        #pragma unroll
        for (int k = 0; k < 8; ++k)
            s += __builtin_nontemporal_load(partial + (size_t)k * E + t);
        out[t] = 1.0f / (1.0f + __expf(-s));
    }
}

// Fallback: whole-row fp16 gather (round-2 structure).
__global__ __launch_bounds__(256) void convert_f32_to_f16(
    const float* __restrict__ h, __half* __restrict__ hh, int n8)
{
    int i = blockIdx.x * blockDim.x + threadIdx.x;
    const int stride = gridDim.x * blockDim.x;
    for (; i < n8; i += stride) {
        float4 a = reinterpret_cast<const float4*>(h)[2 * i + 0];
        float4 b = reinterpret_cast<const float4*>(h)[2 * i + 1];
        __half2 p[4];
        p[0] = __floats2half2_rn(a.x, a.y);
        p[1] = __floats2half2_rn(a.z, a.w);
        p[2] = __floats2half2_rn(b.x, b.y);
        p[3] = __floats2half2_rn(b.z, b.w);
        reinterpret_cast<uint4*>(hh)[i] = *reinterpret_cast<uint4*>(p);
    }
}

__global__ __launch_bounds__(256) void gather_dot_f16(
    const __half* __restrict__ hh,
    const int*    __restrict__ src_idx,
    const int*    __restrict__ dst_idx,
    float*        __restrict__ out,
    int E)
{
    const int lane   = threadIdx.x & 63;
    const int wave   = (blockIdx.x * blockDim.x + threadIdx.x) >> 6;
    const int nwaves = (gridDim.x * blockDim.x) >> 6;
    for (int e = wave; e < E; e += nwaves) {
        const int s = src_idx[e];
        const int d = dst_idx[e];
        uint2 ua = *reinterpret_cast<const uint2*>(hh + (size_t)s * 256 + lane * 4);
        uint2 ub = *reinterpret_cast<const uint2*>(hh + (size_t)d * 256 + lane * 4);
        float2 a0 = __half22float2(*reinterpret_cast<__half2*>(&ua.x));
        float2 a1 = __half22float2(*reinterpret_cast<__half2*>(&ua.y));
        float2 b0 = __half22float2(*reinterpret_cast<__half2*>(&ub.x));
        float2 b1 = __half22float2(*reinterpret_cast<__half2*>(&ub.y));
        float acc = a0.x * b0.x + a0.y * b0.y + a1.x * b1.x + a1.y * b1.y;
        #pragma unroll
        for (int off = 32; off >= 1; off >>= 1)
            acc += __shfl_xor(acc, off, 64);
        if (lane == 0) out[e] = 1.0f / (1.0f + __expf(-acc));
    }
}

__global__ __launch_bounds__(256) void gather_dot_f32(
    const float* __restrict__ h,
    const int*   __restrict__ src_idx,
    const int*   __restrict__ dst_idx,
    float*       __restrict__ out,
    int E)
{
    const int lane   = threadIdx.x & 63;
    const int wave   = (blockIdx.x * blockDim.x + threadIdx.x) >> 6;
    const int nwaves = (gridDim.x * blockDim.x) >> 6;
    for (int e = wave; e < E; e += nwaves) {
        const int s = src_idx[e];
        const int d = dst_idx[e];
        const float4 a = *reinterpret_cast<const float4*>(h + (size_t)s * 256 + lane * 4);
        const float4 b = *reinterpret_cast<const float4*>(h + (size_t)d * 256 + lane * 4);
        float acc = a.x * b.x + a.y * b.y + a.z * b.z + a.w * b.w;
        #pragma unroll
        for (int off = 32; off >= 1; off >>= 1)
            acc += __shfl_xor(acc, off, 64);
        if (lane == 0) out[e] = 1.0f / (1.0f + __expf(-acc));
    }
}

extern "C" void kernel_launch(void* const* d_in, const int* in_sizes, int n_in,
                              void* d_out, int out_size, void* d_ws, size_t ws_size,
                              hipStream_t stream) {
    const float* h   = (const float*)d_in[0];
    const int*   ei  = (const int*)d_in[1];   // [2, E]: src row then dst row
    float*       out = (float*)d_out;

    const int ND = in_sizes[0];               // N * 256
    const int N  = ND / 256;
    const int E  = in_sizes[1] / 2;
    const int* src = ei;
    const int* dst = ei + E;

    const size_t tbl_bytes  = (size_t)ND * sizeof(__half);
    const size_t part_bytes = (size_t)8 * E * sizeof(float);

    if (ws_size >= tbl_bytes + part_bytes) {
        __half* hs      = (__half*)d_ws;
        float*  partial = (float*)((char*)d_ws + tbl_bytes);
        convert_slice_f16<<<2048, 256, 0, stream>>>(h, hs, N);
        slice_gather_dot<<<2048, 256, 0, stream>>>(hs, src, dst, partial, E, N);
        reduce_sigmoid<<<1024, 256, 0, stream>>>(partial, out, E);
    } else if (ws_size >= tbl_bytes) {
        __half* hh = (__half*)d_ws;
        convert_f32_to_f16<<<2048, 256, 0, stream>>>(h, hh, ND / 8);
        gather_dot_f16<<<2048, 256, 0, stream>>>(hh, src, dst, out, E);
    } else {
        gather_dot_f32<<<2048, 256, 0, stream>>>(h, src, dst, out, E);
    }
}

// Round 6
// 46.355 us; speedup vs baseline: 1.6541x; 1.4493x over previous
//
#include <hip/hip_runtime.h>
#include <hip/hip_fp16.h>

// DotProductDecoder: out[e] = sigmoid( dot(h[src[e]], h[dst[e]]) ), D=256.
//
// Round 6: slice tables are L2-resident (R5: FETCH 124->21.9MB) but the
// gather ran latency-bound (~6 TB/s requested-bytes tier across R1/R2/R5
// regardless of data residency). Changes:
//  - per-64-edge batch: coalesced cacheable index loads + __shfl distribute
//    (kills the idx->row dependent-load chain; NT idx loads went to HBM)
//  - 4 lanes/edge, each lane loads matching src+dst 16B chunks: no pairing
//    shuffle, 8 independent 1KB row-load instructions in flight per batch
//  - XCD-affine convert: block b converts slice b&7 (one 128B line per row),
//    so the gather's slice is already dirty-resident in its own XCD L2.

typedef _Float16 half2_raw __attribute__((ext_vector_type(2)));

// XCD-affine transpose-convert. Block b handles slice s=b&7: fp32 columns
// [32s,32s+32) of each row = exactly one 128B line. 16 lanes x float2 per
// row, 4 rows per wave. Writes hs[s][n][32] (64B/row, 256B contiguous per
// wave-quad).
__global__ __launch_bounds__(256) void convert_slice_f16(
    const float* __restrict__ h, __half* __restrict__ hs, int N)
{
    const int s    = blockIdx.x & 7;
    const int lane = threadIdx.x & 63;
    const int r4   = lane >> 4;       // row 0..3 within wave-quad
    const int c    = lane & 15;       // float2 column within slice
    const int wave = (blockIdx.x >> 3) * (blockDim.x >> 6) + (threadIdx.x >> 6);
    const int nw   = (gridDim.x >> 3) * (blockDim.x >> 6);

    for (int n0 = wave * 4; n0 < N; n0 += nw * 4) {
        const int n = n0 + r4;
        if (n < N) {
            float2 v = *reinterpret_cast<const float2*>(
                h + (size_t)n * 256 + s * 32 + c * 2);
            __half2 p = __floats2half2_rn(v.x, v.y);
            *reinterpret_cast<__half2*>(
                hs + ((size_t)s * N + n) * 32 + c * 2) = p;
        }
    }
}

__device__ inline float dot8_f16(const uint4& v, const uint4& w) {
    float acc = 0.0f;
#if __has_builtin(__builtin_amdgcn_fdot2)
    const half2_raw* pa = reinterpret_cast<const half2_raw*>(&v);
    const half2_raw* pb = reinterpret_cast<const half2_raw*>(&w);
    #pragma unroll
    for (int q = 0; q < 4; ++q)
        acc = __builtin_amdgcn_fdot2(pa[q], pb[q], acc, false);
#else
    const __half2* pa = reinterpret_cast<const __half2*>(&v);
    const __half2* pb = reinterpret_cast<const __half2*>(&w);
    #pragma unroll
    for (int q = 0; q < 4; ++q) {
        float2 fa = __half22float2(pa[q]);
        float2 fb = __half22float2(pb[q]);
        acc += fa.x * fb.x + fa.y * fb.y;
    }
#endif
    return acc;
}

// 4 lanes/edge; lane (q = lane&3) holds 16B chunk q of BOTH src and dst
// row-slices. 64-edge batches: 2 coalesced idx loads, shfl-distribute,
// 8 independent row loads, then dot + 2-step reduce + 64B stores.
__global__ __launch_bounds__(256) void slice_gather_dot(
    const __half* __restrict__ hs,      // [8][N][32]
    const int*    __restrict__ src_idx,
    const int*    __restrict__ dst_idx,
    float*        __restrict__ partial, // [8][E]
    int E, int N)
{
    const int slice = blockIdx.x & 7;
    const int lane  = threadIdx.x & 63;
    const int q     = lane & 3;          // 16B chunk within 64B row-slice
    const int g     = lane >> 2;         // edge 0..15 within sub-batch
    const int wsl   = (blockIdx.x >> 3) * (blockDim.x >> 6) + (threadIdx.x >> 6);
    const int nwsl  = (gridDim.x >> 3) * (blockDim.x >> 6);

    const __half* hsl = hs + (size_t)slice * N * 32;
    float* psl = partial + (size_t)slice * E;

    for (int base = wsl * 64; base < E; base += nwsl * 64) {
        const int eL  = base + lane;
        const int eLc = eL < E ? eL : E - 1;
        const int si  = src_idx[eLc];
        const int di  = dst_idx[eLc];

        int sI[4], dI[4];
        #pragma unroll
        for (int sb = 0; sb < 4; ++sb) {
            const int srcLane = sb * 16 + g;
            sI[sb] = __shfl(si, srcLane, 64);
            dI[sb] = __shfl(di, srcLane, 64);
        }

        uint4 va[4], vb[4];
        #pragma unroll
        for (int sb = 0; sb < 4; ++sb) {
            va[sb] = *reinterpret_cast<const uint4*>(
                hsl + (size_t)sI[sb] * 32 + q * 8);
            vb[sb] = *reinterpret_cast<const uint4*>(
                hsl + (size_t)dI[sb] * 32 + q * 8);
        }

        #pragma unroll
        for (int sb = 0; sb < 4; ++sb) {
            float acc = dot8_f16(va[sb], vb[sb]);
            acc += __shfl_xor(acc, 1, 64);
            acc += __shfl_xor(acc, 2, 64);
            const int e = base + sb * 16 + g;
            if (q == 0 && e < E)
                __builtin_nontemporal_store(acc, psl + e);
        }
    }
}

__global__ __launch_bounds__(256) void reduce_sigmoid(
    const float* __restrict__ partial, float* __restrict__ out, int E)
{
    int t = blockIdx.x * blockDim.x + threadIdx.x;
    const int stride = gridDim.x * blockDim.x;
    for (; t < E; t += stride) {
        float s = 0.0f;
        #pragma unroll
        for (int k = 0; k < 8; ++k)
            s += __builtin_nontemporal_load(partial + (size_t)k * E + t);
        out[t] = 1.0f / (1.0f + __expf(-s));
    }
}

// ---- Fallbacks (round-2 structure) ----
__global__ __launch_bounds__(256) void convert_f32_to_f16(
    const float* __restrict__ h, __half* __restrict__ hh, int n8)
{
    int i = blockIdx.x * blockDim.x + threadIdx.x;
    const int stride = gridDim.x * blockDim.x;
    for (; i < n8; i += stride) {
        float4 a = reinterpret_cast<const float4*>(h)[2 * i + 0];
        float4 b = reinterpret_cast<const float4*>(h)[2 * i + 1];
        __half2 p[4];
        p[0] = __floats2half2_rn(a.x, a.y);
        p[1] = __floats2half2_rn(a.z, a.w);
        p[2] = __floats2half2_rn(b.x, b.y);
        p[3] = __floats2half2_rn(b.z, b.w);
        reinterpret_cast<uint4*>(hh)[i] = *reinterpret_cast<uint4*>(p);
    }
}

__global__ __launch_bounds__(256) void gather_dot_f16(
    const __half* __restrict__ hh,
    const int*    __restrict__ src_idx,
    const int*    __restrict__ dst_idx,
    float*        __restrict__ out,
    int E)
{
    const int lane   = threadIdx.x & 63;
    const int wave   = (blockIdx.x * blockDim.x + threadIdx.x) >> 6;
    const int nwaves = (gridDim.x * blockDim.x) >> 6;
    for (int e = wave; e < E; e += nwaves) {
        const int s = src_idx[e];
        const int d = dst_idx[e];
        uint2 ua = *reinterpret_cast<const uint2*>(hh + (size_t)s * 256 + lane * 4);
        uint2 ub = *reinterpret_cast<const uint2*>(hh + (size_t)d * 256 + lane * 4);
        float2 a0 = __half22float2(*reinterpret_cast<__half2*>(&ua.x));
        float2 a1 = __half22float2(*reinterpret_cast<__half2*>(&ua.y));
        float2 b0 = __half22float2(*reinterpret_cast<__half2*>(&ub.x));
        float2 b1 = __half22float2(*reinterpret_cast<__half2*>(&ub.y));
        float acc = a0.x * b0.x + a0.y * b0.y + a1.x * b1.x + a1.y * b1.y;
        #pragma unroll
        for (int off = 32; off >= 1; off >>= 1)
            acc += __shfl_xor(acc, off, 64);
        if (lane == 0) out[e] = 1.0f / (1.0f + __expf(-acc));
    }
}

__global__ __launch_bounds__(256) void gather_dot_f32(
    const float* __restrict__ h,
    const int*   __restrict__ src_idx,
    const int*   __restrict__ dst_idx,
    float*       __restrict__ out,
    int E)
{
    const int lane   = threadIdx.x & 63;
    const int wave   = (blockIdx.x * blockDim.x + threadIdx.x) >> 6;
    const int nwaves = (gridDim.x * blockDim.x) >> 6;
    for (int e = wave; e < E; e += nwaves) {
        const int s = src_idx[e];
        const int d = dst_idx[e];
        const float4 a = *reinterpret_cast<const float4*>(h + (size_t)s * 256 + lane * 4);
        const float4 b = *reinterpret_cast<const float4*>(h + (size_t)d * 256 + lane * 4);
        float acc = a.x * b.x + a.y * b.y + a.z * b.z + a.w * b.w;
        #pragma unroll
        for (int off = 32; off >= 1; off >>= 1)
            acc += __shfl_xor(acc, off, 64);
        if (lane == 0) out[e] = 1.0f / (1.0f + __expf(-acc));
    }
}

extern "C" void kernel_launch(void* const* d_in, const int* in_sizes, int n_in,
                              void* d_out, int out_size, void* d_ws, size_t ws_size,
                              hipStream_t stream) {
    const float* h   = (const float*)d_in[0];
    const int*   ei  = (const int*)d_in[1];   // [2, E]: src row then dst row
    float*       out = (float*)d_out;

    const int ND = in_sizes[0];               // N * 256
    const int N  = ND / 256;
    const int E  = in_sizes[1] / 2;
    const int* src = ei;
    const int* dst = ei + E;

    const size_t tbl_bytes  = (size_t)ND * sizeof(__half);
    const size_t part_bytes = (size_t)8 * E * sizeof(float);

    if (ws_size >= tbl_bytes + part_bytes) {
        __half* hs      = (__half*)d_ws;
        float*  partial = (float*)((char*)d_ws + tbl_bytes);
        convert_slice_f16<<<2048, 256, 0, stream>>>(h, hs, N);
        slice_gather_dot<<<2048, 256, 0, stream>>>(hs, src, dst, partial, E, N);
        reduce_sigmoid<<<1024, 256, 0, stream>>>(partial, out, E);
    } else if (ws_size >= tbl_bytes) {
        __half* hh = (__half*)d_ws;
        convert_f32_to_f16<<<2048, 256, 0, stream>>>(h, hh, ND / 8);
        gather_dot_f16<<<2048, 256, 0, stream>>>(hh, src, dst, out, E);
    } else {
        gather_dot_f32<<<2048, 256, 0, stream>>>(h, src, dst, out, E);
    }
}